// Round 6
// baseline (2104.403 us; speedup 1.0000x reference)
//
#include <hip/hip_runtime.h>
#include <cmath>

#define BB 64
#define TT 2048
#define FF 64
#define HH 160
#define G3 480
#define TC 128            // time-chunk length
#define NC (TT / TC)      // 16 chunks

#define L2E  1.44269504088896340736f
#define TL2E 2.88539008177792681472f

typedef unsigned int u32;
typedef _Float16 half8 __attribute__((ext_vector_type(8)));
typedef _Float16 half2v __attribute__((ext_vector_type(2)));
typedef float f32x4 __attribute__((ext_vector_type(4)));

__device__ __forceinline__ unsigned short f2h(float v) {
    _Float16 h = (_Float16)v;
    return __builtin_bit_cast(unsigned short, h);
}
__device__ __forceinline__ u32 packh2(float a, float b) {
    return (u32)f2h(a) | ((u32)f2h(b) << 16);
}
__device__ __forceinline__ u32 packhh(_Float16 a, _Float16 b) {
    return (u32)__builtin_bit_cast(unsigned short, a)
         | ((u32)__builtin_bit_cast(unsigned short, b) << 16);
}
__device__ __forceinline__ float h2lo(u32 p) {
    return (float)__builtin_bit_cast(half2v, p)[0];
}
__device__ __forceinline__ float h2hi(u32 p) {
    return (float)__builtin_bit_cast(half2v, p)[1];
}
// fast 1-ulp reciprocal / exp2 (avoid IEEE div + libm: no fast-math in harness)
__device__ __forceinline__ float frcp(float v) { return __builtin_amdgcn_rcpf(v); }
#if __has_builtin(__builtin_amdgcn_exp2f)
__device__ __forceinline__ float fexp2(float v) { return __builtin_amdgcn_exp2f(v); }
#else
__device__ __forceinline__ float fexp2(float v) { return __expf(v * 0.69314718055994530942f); }
#endif
__device__ __forceinline__ float gelu_exact(float v) {
    return 0.5f * v * (1.f + erff(v * 0.70710678118654752f));
}
// barrier that waits only on LDS ops (NOT vmcnt)
__device__ __forceinline__ void barrier_lgkm() {
    asm volatile("s_waitcnt lgkmcnt(0)\ns_barrier" ::: "memory");
}
__device__ __forceinline__ half8 load_wrow8(const float* p) {
    const float4* q = (const float4*)p;
    float4 a = q[0], b = q[1];
    half8 r;
    r[0] = (_Float16)a.x; r[1] = (_Float16)a.y; r[2] = (_Float16)a.z; r[3] = (_Float16)a.w;
    r[4] = (_Float16)b.x; r[5] = (_Float16)b.y; r[6] = (_Float16)b.z; r[7] = (_Float16)b.w;
    return r;
}
// scaled variant: w -> f16(w * s). Used to fold log2(e) into gate weights so
// the scan's sigmoid/tanh use raw v_exp_f32 (exp2) with no pre-multiply.
__device__ __forceinline__ half8 load_wrow8s(const float* p, float s) {
    const float4* q = (const float4*)p;
    float4 a = q[0], b = q[1];
    half8 r;
    r[0] = (_Float16)(a.x * s); r[1] = (_Float16)(a.y * s);
    r[2] = (_Float16)(a.z * s); r[3] = (_Float16)(a.w * s);
    r[4] = (_Float16)(b.x * s); r[5] = (_Float16)(b.y * s);
    r[6] = (_Float16)(b.z * s); r[7] = (_Float16)(b.w * s);
    return r;
}
// split f32x8 into hi(f16) + lo(f16 of residual): hi+lo reproduces f32 to ~2^-22
__device__ __forceinline__ void split8(const float* v, half8& hi, half8& lo) {
    #pragma unroll
    for (int j = 0; j < 8; ++j) {
        _Float16 h = (_Float16)v[j];
        hi[j] = h;
        lo[j] = (_Float16)(v[j] - (float)h);
    }
}
#define MM16(A_, B_, C_) __builtin_amdgcn_mfma_f32_16x16x32_f16(A_, B_, C_, 0, 0, 0)

// ---------------------------------------------------------------------------
// K1: dilated conv + BN + exact GELU via MFMA (split-f16 for f32 accuracy).
// x tile staged into LDS once (coalesced), pre-split into f16 hi/lo planes.
// R6: z stored via LDS transpose tile -> coalesced 128B-segment global
// stores (was: 64 scattered 8B lines per wave-store).
// ---------------------------------------------------------------------------
__global__ __launch_bounds__(256) void conv_mfma_kernel(
    const float* __restrict__ x, const float* __restrict__ mix_w,
    const float* __restrict__ bn_g, const float* __restrict__ bn_b,
    const float* __restrict__ bn_m, const float* __restrict__ bn_v,
    u32* __restrict__ z_out)
{
    // per row (136 f16 = 68 u32 = 272 B): [hi 64 f16][lo 64 f16][pad 8 f16]
    __shared__ __align__(16) u32 xs[132 * 68];
    __shared__ __align__(8)  u32 zt[16 * 34];   // transpose tile [t16][32 u32 +pad2]

    const int b   = blockIdx.y;
    const int t0  = blockIdx.x * 128;
    const int tid = threadIdx.x;
    const int wv = tid >> 6;          // 0..3 : fo-tile of 16
    const int lane = tid & 63;
    const int lane15 = lane & 15;
    const int quad = lane >> 4;

    // ---- stage x rows t0-2 .. t0+129, split hi/lo ----
    {
        const float* xb = x + (size_t)b * TT * FF;
        for (int idx = tid; idx < 132 * 32; idx += 256) {   // f-pairs
            const int row = idx >> 5;
            const int fp  = (idx & 31) * 2;
            const int t = t0 - 2 + row;
            float v0 = 0.f, v1 = 0.f;
            if (t >= 0 && t < TT) {
                float2 v = *(const float2*)(xb + (size_t)t * FF + fp);
                v0 = v.x; v1 = v.y;
            }
            _Float16 h0 = (_Float16)v0, h1 = (_Float16)v1;
            _Float16 l0 = (_Float16)(v0 - (float)h0);
            _Float16 l1 = (_Float16)(v1 - (float)h1);
            u32* rw = xs + row * 68;
            rw[(fp >> 1)]      = packhh(h0, h1);
            rw[32 + (fp >> 1)] = packhh(l0, l1);
        }
    }

    // ---- A fragments (weights) ----
    half8 Ahi[6], Alo[6];
    {
        const int fo = wv * 16 + lane15;
        const float* wrow = mix_w + fo * 192;      // mix_w[fo][fi][k]
        #pragma unroll
        for (int s = 0; s < 6; ++s) {
            float wf[8];
            #pragma unroll
            for (int j = 0; j < 8; ++j) {
                int kap = s * 32 + quad * 8 + j;   // kappa = k*64 + fi
                wf[j] = wrow[(kap & 63) * 3 + (kap >> 6)];
            }
            split8(wf, Ahi[s], Alo[s]);
        }
    }
    float sc[4], sh[4];
    #pragma unroll
    for (int r = 0; r < 4; ++r) {
        int f = wv * 16 + quad * 4 + r;
        float scl = bn_g[f] * rsqrtf(bn_v[f] + 1e-5f);
        sc[r] = scl; sh[r] = bn_b[f] - bn_m[f] * scl;
    }

    __syncthreads();

    u32* zrow = z_out + (size_t)(b >> 4) * TT * 512 + (b & 15) * 32;
    const int srow = tid >> 4;        // 0..15: t-row for coalesced store
    const int sc2  = tid & 15;        // uint2 column

    for (int tt = 0; tt < 8; ++tt) {
        f32x4 C = {0.f, 0.f, 0.f, 0.f};
        #pragma unroll
        for (int s = 0; s < 6; ++s) {
            // B: lane15 = t chain, slice s -> k = s>>1, fi half = (s&1)*32
            const int row = tt * 16 + lane15 + 2 * (s >> 1);
            const u32* rp = xs + row * 68 + (s & 1) * 16 + quad * 4;
            half8 Bhi = __builtin_bit_cast(half8, *(const uint4*)(rp));
            half8 Blo = __builtin_bit_cast(half8, *(const uint4*)(rp + 32));
            C = MM16(Ahi[s], Bhi, C);
            C = MM16(Ahi[s], Blo, C);
            C = MM16(Alo[s], Bhi, C);
        }
        float z0 = gelu_exact(fmaf(C[0], sc[0], sh[0]));
        float z1 = gelu_exact(fmaf(C[1], sc[1], sh[1]));
        float z2 = gelu_exact(fmaf(C[2], sc[2], sh[2]));
        float z3 = gelu_exact(fmaf(C[3], sc[3], sh[3]));
        const u32 q0 = packh2(z0, z1);
        const u32 q1 = packh2(z2, z3);
        __syncthreads();   // previous tt's zt reads complete
        *(uint2*)(zt + lane15 * 34 + wv * 8 + quad * 2) = (uint2){q0, q1};
        __syncthreads();   // zt fully written
        uint2 v = *(const uint2*)(zt + srow * 34 + sc2 * 2);
        *(uint2*)(zrow + (size_t)(t0 + tt * 16 + srow) * 512 + sc2 * 2) = v;
    }
}

// ---------------------------------------------------------------------------
// GEMM device body (MFMA): xg[t][tile][chain][n'/2] f16 pairs. 512 workers.
// Weights/biases pre-scaled by L2E (r,z rows: tiles 0..19) / TL2E (n rows:
// tiles 20..29) so the scan's gate transcendentals are raw exp2.
// ---------------------------------------------------------------------------
#define DECLAI(i) half8 A##i##_0, A##i##_1, A##i##_2, A##i##_3, A##i##_4;
#define GLOADA(i) { int tl = wv4 + (i); int rowc = tl < 30 ? tl * 16 + lane15 : 479; \
    float sA = tl < 20 ? L2E : TL2E;                                                 \
    const float* wp = W + (size_t)rowc * K + quad * 8;                               \
    A##i##_0 = load_wrow8s(wp, sA); A##i##_1 = load_wrow8s(wp + 32, sA);             \
    if (KT > 2) { A##i##_2 = load_wrow8s(wp + 64, sA);                               \
                  A##i##_3 = load_wrow8s(wp + 96, sA);                               \
                  A##i##_4 = load_wrow8s(wp + 128, sA); }                            \
    else { A##i##_2 = A##i##_0; A##i##_3 = A##i##_0; A##i##_4 = A##i##_0; } }
#define GMM(i, kt) C##i = MM16(A##i##_##kt, Bk##kt, C##i);

template<int K, int KT, int TG>
__device__ __forceinline__ void gemm_body(
    const unsigned short* __restrict__ in,  // f16 [blk][rows][16 chains][K]
    size_t in_blk_stride, int t_off,
    const float* __restrict__ W, const float* __restrict__ b_ih,
    const float* __restrict__ b_hh, u32* __restrict__ xg,
    int gidx, int tid)
{
    if (tid >= 512) return;
    const int wv4 = (tid >> 6) * 4;
    const int lane = tid & 63;
    const int lane15 = lane & 15;
    const int quad = lane >> 4;
    const int blk = gidx >> 4;            // 0..3 chain-block
    const int tbase = (gidx & 15) * TG;   // 16 t-tiles per chunk

    DECLAI(0) DECLAI(1) DECLAI(2) DECLAI(3)
    GLOADA(0) GLOADA(1) GLOADA(2) GLOADA(3)

    f32x4 BIAS0, BIAS1, BIAS2, BIAS3;
    #define GBIAS(i) { int tl = wv4 + (i); int rowb = tl < 30 ? tl * 16 + quad * 4 : 476; \
        float sB = tl < 20 ? L2E : TL2E;                                                  \
        float4 bi = *(const float4*)(b_ih + rowb);                                        \
        if (tl < 20) { float4 bh = *(const float4*)(b_hh + rowb);                         \
            bi.x += bh.x; bi.y += bh.y; bi.z += bh.z; bi.w += bh.w; }                     \
        BIAS##i[0] = bi.x * sB; BIAS##i[1] = bi.y * sB;                                   \
        BIAS##i[2] = bi.z * sB; BIAS##i[3] = bi.w * sB; }
    GBIAS(0) GBIAS(1) GBIAS(2) GBIAS(3)
    #undef GBIAS

    const unsigned short* inb = in + (size_t)blk * in_blk_stride;
    u32* xgb = xg + (size_t)blk * TC * 3840;

    for (int t = 0; t < TG; ++t) {
        const int tt = tbase + t;
        const unsigned short* ip =
            inb + ((size_t)(t_off + tt) * 16 + lane15) * K + quad * 8;
        half8 Bk0 = __builtin_bit_cast(half8, *(const uint4*)(ip));
        half8 Bk1 = __builtin_bit_cast(half8, *(const uint4*)(ip + 32));
        half8 Bk2 = Bk0, Bk3 = Bk0, Bk4 = Bk0;
        if (KT > 2) {
            Bk2 = __builtin_bit_cast(half8, *(const uint4*)(ip + 64));
            Bk3 = __builtin_bit_cast(half8, *(const uint4*)(ip + 96));
            Bk4 = __builtin_bit_cast(half8, *(const uint4*)(ip + 128));
        }
        f32x4 C0 = BIAS0, C1 = BIAS1, C2 = BIAS2, C3 = BIAS3;
        GMM(0, 0) GMM(1, 0) GMM(2, 0) GMM(3, 0)
        GMM(0, 1) GMM(1, 1) GMM(2, 1) GMM(3, 1)
        if (KT > 2) {
            GMM(0, 2) GMM(1, 2) GMM(2, 2) GMM(3, 2)
            GMM(0, 3) GMM(1, 3) GMM(2, 3) GMM(3, 3)
            GMM(0, 4) GMM(1, 4) GMM(2, 4) GMM(3, 4)
        }
        #define GSTORE(i) { int tl = wv4 + (i); if (tl < 30) {                      \
            u32 q0 = packh2(C##i[0], C##i[1]);                                      \
            u32 q1 = packh2(C##i[2], C##i[3]);                                      \
            *(uint2*)(xgb + (((size_t)tt * 30 + tl) * 16 + lane15) * 8 + quad * 2)  \
                = (uint2){q0, q1}; } }
        GSTORE(0) GSTORE(1) GSTORE(2) GSTORE(3)
        #undef GSTORE
    }
}

// ---------------------------------------------------------------------------
// Scan device body (MFMA): 640 threads, 10 waves, 16 chains.
// exp2-folded gates; x-gate/bias absorbed into MFMA C-init; 4-deep prefetch
// ring with private reg sets; strength-reduced pointers; static LDS parity.
// ---------------------------------------------------------------------------
#define DECLW(nm) half8 nm##0, nm##1, nm##2, nm##3, nm##4;
#define LOADWHS(nm, tb, S) { const float* wp = w_hh + (size_t)((tb) * 16 + lane15) * HH + quad * 8; \
    nm##0 = load_wrow8s(wp, S);       nm##1 = load_wrow8s(wp + 32, S);                              \
    nm##2 = load_wrow8s(wp + 64, S);  nm##3 = load_wrow8s(wp + 96, S);                              \
    nm##4 = load_wrow8s(wp + 128, S); }

template<bool WRITE_H>
__device__ __forceinline__ void scan_body(
    const u32* __restrict__ xg,          // f16 pairs [4][TC][30][16][8] u32
    const float* __restrict__ w_hh, const float* __restrict__ b_hh,
    float* __restrict__ h_state,         // [64][160] f32 carry
    u32* __restrict__ h_out32,           // [4][TC][16][80] u32 (if WRITE_H)
    int first, int blk, int tid, uint4* h_lds)
{
    const int wv = tid >> 6;
    const int lane = tid & 63;
    const int lane15 = lane & 15;
    const int quad = lane >> 4;

    DECLW(Ar) DECLW(Az) DECLW(An)
    LOADWHS(Ar, wv, L2E) LOADWHS(Az, 10 + wv, L2E) LOADWHS(An, 20 + wv, TL2E)

    float4 bhn = *(const float4*)(b_hh + 320 + wv * 16 + quad * 4);
    bhn.x *= TL2E; bhn.y *= TL2E; bhn.z *= TL2E; bhn.w *= TL2E;

    float4 ho = {0.f, 0.f, 0.f, 0.f};
    float* hsp = h_state + (size_t)(blk * 16 + lane15) * HH;
    if (!first) ho = *(const float4*)(hsp + wv * 16 + quad * 4);

    const int hwidx = (((wv >> 1) * 4 + ((wv & 1) * 2 + (quad >> 1))) * 16 + lane15) * 4
                    + (quad & 1) * 2;
    u32* hl32 = (u32*)h_lds;
    u32* HW0 = hl32 + hwidx;             // write ptr, LDS parity 0
    u32* HW1 = hl32 + 1280 + hwidx;      // write ptr, LDS parity 1
    *(uint2*)HW0 = (uint2){packh2(ho.x, ho.y), packh2(ho.z, ho.w)};

    const u32* xgb = xg + (size_t)blk * TC * 3840;
    const int xo_r = ((wv)      * 16 + lane15) * 8 + quad * 2;
    const int xo_z = ((10 + wv) * 16 + lane15) * 8 + quad * 2;
    const int xo_n = ((20 + wv) * 16 + lane15) * 8 + quad * 2;

    // 4-deep prefetch ring, private register set per sub-step
    uint2 xrP0 = *(const uint2*)(xgb + 0 * 3840 + xo_r);
    uint2 xzP0 = *(const uint2*)(xgb + 0 * 3840 + xo_z);
    uint2 xnP0 = *(const uint2*)(xgb + 0 * 3840 + xo_n);
    uint2 xrP1 = *(const uint2*)(xgb + 1 * 3840 + xo_r);
    uint2 xzP1 = *(const uint2*)(xgb + 1 * 3840 + xo_z);
    uint2 xnP1 = *(const uint2*)(xgb + 1 * 3840 + xo_n);
    uint2 xrP2 = *(const uint2*)(xgb + 2 * 3840 + xo_r);
    uint2 xzP2 = *(const uint2*)(xgb + 2 * 3840 + xo_z);
    uint2 xnP2 = *(const uint2*)(xgb + 2 * 3840 + xo_n);
    uint2 xrP3 = *(const uint2*)(xgb + 3 * 3840 + xo_r);
    uint2 xzP3 = *(const uint2*)(xgb + 3 * 3840 + xo_z);
    uint2 xnP3 = *(const uint2*)(xgb + 3 * 3840 + xo_n);
    const u32* pf_r = xgb + 4 * 3840 + xo_r;   // t+4 prefetch base
    const u32* pf_z = xgb + 4 * 3840 + xo_z;
    const u32* pf_n = xgb + 4 * 3840 + xo_n;

    u32* hp = WRITE_H
            ? h_out32 + (size_t)blk * TC * 1280 + (size_t)lane15 * 80 + wv * 8 + quad * 2
            : nullptr;
    __syncthreads();

    #define SCAN_STEP(RBOFF, HWP, XR, XZ, XN, PFO, HPO)                              \
    {                                                                                \
        const uint4* hb = h_lds + (RBOFF);                                           \
        uint4 b0 = hb[lane];       uint4 b1 = hb[64 + lane];                         \
        uint4 b2 = hb[128 + lane]; uint4 b3 = hb[192 + lane];                        \
        uint4 b4 = hb[256 + lane];                                                   \
        f32x4 Cr, Cz, Cn;                                                            \
        Cr[0] = h2lo(XR.x); Cr[1] = h2hi(XR.x); Cr[2] = h2lo(XR.y); Cr[3] = h2hi(XR.y); \
        Cz[0] = h2lo(XZ.x); Cz[1] = h2hi(XZ.x); Cz[2] = h2lo(XZ.y); Cz[3] = h2hi(XZ.y); \
        Cn[0] = bhn.x; Cn[1] = bhn.y; Cn[2] = bhn.z; Cn[3] = bhn.w;                  \
        float xn0 = h2lo(XN.x), xn1 = h2hi(XN.x), xn2 = h2lo(XN.y), xn3 = h2hi(XN.y); \
        XR = *(const uint2*)(pf_r + (PFO));                                          \
        XZ = *(const uint2*)(pf_z + (PFO));                                          \
        XN = *(const uint2*)(pf_n + (PFO));                                          \
        half8 B0 = __builtin_bit_cast(half8, b0);                                    \
        Cr = MM16(Ar0, B0, Cr); Cz = MM16(Az0, B0, Cz); Cn = MM16(An0, B0, Cn);      \
        half8 B1 = __builtin_bit_cast(half8, b1);                                    \
        Cr = MM16(Ar1, B1, Cr); Cz = MM16(Az1, B1, Cz); Cn = MM16(An1, B1, Cn);      \
        half8 B2 = __builtin_bit_cast(half8, b2);                                    \
        Cr = MM16(Ar2, B2, Cr); Cz = MM16(Az2, B2, Cz); Cn = MM16(An2, B2, Cn);      \
        half8 B3 = __builtin_bit_cast(half8, b3);                                    \
        Cr = MM16(Ar3, B3, Cr); Cz = MM16(Az3, B3, Cz); Cn = MM16(An3, B3, Cn);      \
        half8 B4 = __builtin_bit_cast(half8, b4);                                    \
        Cr = MM16(Ar4, B4, Cr); Cz = MM16(Az4, B4, Cz); Cn = MM16(An4, B4, Cn);      \
        {                                                                            \
            float r0 = frcp(1.f + fexp2(-Cr[0]));                                    \
            float r1 = frcp(1.f + fexp2(-Cr[1]));                                    \
            float r2 = frcp(1.f + fexp2(-Cr[2]));                                    \
            float r3 = frcp(1.f + fexp2(-Cr[3]));                                    \
            float u0 = frcp(1.f + fexp2(-Cz[0]));                                    \
            float u1 = frcp(1.f + fexp2(-Cz[1]));                                    \
            float u2 = frcp(1.f + fexp2(-Cz[2]));                                    \
            float u3 = frcp(1.f + fexp2(-Cz[3]));                                    \
            float e0 = fexp2(fmaf(r0, Cn[0], xn0));                                  \
            float e1 = fexp2(fmaf(r1, Cn[1], xn1));                                  \
            float e2 = fexp2(fmaf(r2, Cn[2], xn2));                                  \
            float e3 = fexp2(fmaf(r3, Cn[3], xn3));                                  \
            float n0 = fmaf(-2.f, frcp(e0 + 1.f), 1.f);                              \
            float n1 = fmaf(-2.f, frcp(e1 + 1.f), 1.f);                              \
            float n2 = fmaf(-2.f, frcp(e2 + 1.f), 1.f);                              \
            float n3 = fmaf(-2.f, frcp(e3 + 1.f), 1.f);                              \
            ho.x = fmaf(u0, ho.x - n0, n0);                                          \
            ho.y = fmaf(u1, ho.y - n1, n1);                                          \
            ho.z = fmaf(u2, ho.z - n2, n2);                                          \
            ho.w = fmaf(u3, ho.w - n3, n3);                                          \
        }                                                                            \
        const u32 p0 = packh2(ho.x, ho.y);                                           \
        const u32 p1 = packh2(ho.z, ho.w);                                           \
        *(uint2*)(HWP) = (uint2){p0, p1};                                            \
        if (WRITE_H) {                                                               \
            *(uint2*)(hp + (HPO)) = (uint2){p0, p1};                                 \
        }                                                                            \
        barrier_lgkm();                                                              \
    }

    for (int t4 = 0; t4 < TC; t4 += 4) {
        SCAN_STEP(0,   HW1, xrP0, xzP0, xnP0, 0 * 3840, 0 * 1280)
        SCAN_STEP(320, HW0, xrP1, xzP1, xnP1, 1 * 3840, 1 * 1280)
        SCAN_STEP(0,   HW1, xrP2, xzP2, xnP2, 2 * 3840, 2 * 1280)
        SCAN_STEP(320, HW0, xrP3, xzP3, xnP3, 3 * 3840, 3 * 1280)
        pf_r += 4 * 3840; pf_z += 4 * 3840; pf_n += 4 * 3840;
        if (WRITE_H) hp += 4 * 1280;
    }
    #undef SCAN_STEP

    *(float4*)(hsp + wv * 16 + quad * 4) = ho;
}

// ---------------------------------------------------------------------------
// K2: pipelined mega-dispatch. Stage k runs concurrently:
//   blocks 0..3    : scan1 chunk k-1
//   blocks 4..7    : scan2 chunk k-3
//   blocks 8..71   : gemm1 chunk k      (64 blocks, TG=8)
//   blocks 72..135 : gemm2 chunk k-2    (64 blocks, TG=8)
// All producer->consumer edges cross a dispatch boundary; parity (chunk&1)
// double-buffers xg1/xg2/h1c against same-dispatch writers.
// __launch_bounds__(640, 1): every block is alone on its CU (136 blocks,
// 256 CUs) -- default occupancy-driven VGPR cap (84) starved the scan's
// prefetch ring / store-data rotation, forcing per-step vmcnt waits.
// NOTE: scan prefetch over-reads up to 4 steps past its chunk region; all such
// addresses stay inside the ws allocation (next buffer), values dead.
// ---------------------------------------------------------------------------
__global__ __launch_bounds__(640, 1) void pipe_stage(
    const u32* __restrict__ z,           // [4][TT][16][32] u32
    u32* __restrict__ xg1,               // 2 x [4][TC][3840] u32
    u32* __restrict__ xg2,
    u32* __restrict__ h1c,               // 2 x [4][TC][1280] u32
    float* __restrict__ h1s, float* __restrict__ h2s,
    const float* __restrict__ w_ih1, const float* __restrict__ b_ih1,
    const float* __restrict__ w_hh1, const float* __restrict__ b_hh1,
    const float* __restrict__ w_ih2, const float* __restrict__ b_ih2,
    const float* __restrict__ w_hh2, const float* __restrict__ b_hh2,
    int k)
{
    __shared__ uint4 h_lds[2 * 320];
    const int bx = blockIdx.x;
    const int tid = threadIdx.x;
    const size_t XGCH = (size_t)4 * TC * 3840;   // u32 per parity buffer
    const size_t H1CH = (size_t)4 * TC * 1280;

    if (bx < 4) {
        const int c = k - 1;
        if (c < 0 || c >= NC) return;
        scan_body<true>(xg1 + (c & 1) * XGCH, w_hh1, b_hh1, h1s,
                        h1c + (c & 1) * H1CH, c == 0, bx, tid, h_lds);
    } else if (bx < 8) {
        const int c = k - 3;
        if (c < 0 || c >= NC) return;
        scan_body<false>(xg2 + (c & 1) * XGCH, w_hh2, b_hh2, h2s,
                         nullptr, c == 0, bx - 4, tid, h_lds);
    } else if (bx < 72) {
        const int c = k;
        if (c >= NC) return;
        gemm_body<64, 2, 8>((const unsigned short*)z, (size_t)TT * 1024, c * TC,
                            w_ih1, b_ih1, b_hh1, xg1 + (c & 1) * XGCH, bx - 8, tid);
    } else {
        const int c = k - 2;
        if (c < 0 || c >= NC) return;
        gemm_body<160, 5, 8>((const unsigned short*)(h1c + (c & 1) * H1CH),
                             (size_t)TC * 2560, 0,
                             w_ih2, b_ih2, b_hh2, xg2 + (c & 1) * XGCH, bx - 72, tid);
    }
}

// ---------------------------------------------------------------------------
// K3: MLP head from h2 final state.
// ---------------------------------------------------------------------------
__global__ __launch_bounds__(256) void head_kernel(
    const float* __restrict__ h_state,
    const float* __restrict__ hw1, const float* __restrict__ hb1,
    const float* __restrict__ hw2, const float* __restrict__ hb2,
    float* __restrict__ out)
{
    const int b = blockIdx.x;
    const int tid = threadIdx.x;
    __shared__ float hf[HH];
    __shared__ float q[80];
    if (tid < HH) hf[tid] = h_state[b * HH + tid];
    __syncthreads();
    if (tid < 80) {
        float a = hb1[tid];
        const float* wr = hw1 + (size_t)tid * HH;
        #pragma unroll 8
        for (int i = 0; i < HH; ++i) a = fmaf(wr[i], hf[i], a);
        q[tid] = gelu_exact(a);
    }
    __syncthreads();
    if (tid < 2) {
        float o = hb2[tid];
        const float* wr = hw2 + tid * 80;
        #pragma unroll 8
        for (int j = 0; j < 80; ++j) o = fmaf(wr[j], q[j], o);
        out[b * 2 + tid] = o;
    }
}

// ---------------------------------------------------------------------------
extern "C" void kernel_launch(void* const* d_in, const int* in_sizes, int n_in,
                              void* d_out, int out_size, void* d_ws, size_t ws_size,
                              hipStream_t stream)
{
    const float* x     = (const float*)d_in[0];
    const float* mix_w = (const float*)d_in[1];
    const float* bn_g  = (const float*)d_in[2];
    const float* bn_b  = (const float*)d_in[3];
    const float* bn_m  = (const float*)d_in[4];
    const float* bn_v  = (const float*)d_in[5];
    const float* w_ih1 = (const float*)d_in[6];
    const float* w_hh1 = (const float*)d_in[7];
    const float* b_ih1 = (const float*)d_in[8];
    const float* b_hh1 = (const float*)d_in[9];
    const float* w_ih2 = (const float*)d_in[10];
    const float* w_hh2 = (const float*)d_in[11];
    const float* b_ih2 = (const float*)d_in[12];
    const float* b_hh2 = (const float*)d_in[13];
    const float* hw1   = (const float*)d_in[14];
    const float* hb1   = (const float*)d_in[15];
    const float* hw2   = (const float*)d_in[16];
    const float* hb2   = (const float*)d_in[17];
    float* out = (float*)d_out;

    // ws (53.6 MB, proven-safe):
    //   z    f16 [4][T][16][64]            16.78 MB
    //   xg1  f16 2x[4][TC][30][16][16]     15.73 MB
    //   xg2  f16 2x[4][TC][30][16][16]     15.73 MB
    //   h1c  f16 2x[4][TC][16][160]         5.24 MB
    //   h1s,h2s f32 [64][160]               2 x 40 KB
    char* p = (char*)d_ws;
    u32* z_ws  = (u32*)p;  p += (size_t)BB * TT * 32 * 4;
    u32* xg1_ws = (u32*)p; p += (size_t)2 * 4 * TC * 3840 * 4;
    u32* xg2_ws = (u32*)p; p += (size_t)2 * 4 * TC * 3840 * 4;
    u32* h1c_ws = (u32*)p; p += (size_t)2 * 4 * TC * 1280 * 4;
    float* h1s = (float*)p; p += (size_t)BB * HH * 4;
    float* h2s = (float*)p;

    conv_mfma_kernel<<<dim3(16, BB), 256, 0, stream>>>(
        x, mix_w, bn_g, bn_b, bn_m, bn_v, z_ws);

    for (int k = 0; k <= NC + 2; ++k) {
        pipe_stage<<<136, 640, 0, stream>>>(
            z_ws, xg1_ws, xg2_ws, h1c_ws, h1s, h2s,
            w_ih1, b_ih1, w_hh1, b_hh1,
            w_ih2, b_ih2, w_hh2, b_hh2, k);
    }

    head_kernel<<<BB, 256, 0, stream>>>(h2s, hw1, hb1, hw2, hb2, out);
}

// Round 7
// 1874.940 us; speedup vs baseline: 1.1224x; 1.1224x over previous
//
#include <hip/hip_runtime.h>
#include <cmath>

#define BB 64
#define TT 2048
#define FF 64
#define HH 160
#define G3 480
#define TC 128            // time-chunk length
#define NC (TT / TC)      // 16 chunks

#define L2E  1.44269504088896340736f
#define TL2E 2.88539008177792681472f

typedef unsigned int u32;
typedef _Float16 half8 __attribute__((ext_vector_type(8)));
typedef _Float16 half2v __attribute__((ext_vector_type(2)));
typedef float f32x4 __attribute__((ext_vector_type(4)));

__device__ __forceinline__ unsigned short f2h(float v) {
    _Float16 h = (_Float16)v;
    return __builtin_bit_cast(unsigned short, h);
}
__device__ __forceinline__ u32 packh2(float a, float b) {
    return (u32)f2h(a) | ((u32)f2h(b) << 16);
}
__device__ __forceinline__ u32 packhh(_Float16 a, _Float16 b) {
    return (u32)__builtin_bit_cast(unsigned short, a)
         | ((u32)__builtin_bit_cast(unsigned short, b) << 16);
}
__device__ __forceinline__ float h2lo(u32 p) {
    return (float)__builtin_bit_cast(half2v, p)[0];
}
__device__ __forceinline__ float h2hi(u32 p) {
    return (float)__builtin_bit_cast(half2v, p)[1];
}
// fast 1-ulp reciprocal / exp2 (avoid IEEE div + libm: no fast-math in harness)
__device__ __forceinline__ float frcp(float v) { return __builtin_amdgcn_rcpf(v); }
#if __has_builtin(__builtin_amdgcn_exp2f)
__device__ __forceinline__ float fexp2(float v) { return __builtin_amdgcn_exp2f(v); }
#else
__device__ __forceinline__ float fexp2(float v) { return __expf(v * 0.69314718055994530942f); }
#endif
__device__ __forceinline__ float gelu_exact(float v) {
    return 0.5f * v * (1.f + erff(v * 0.70710678118654752f));
}
// barrier that waits only on LDS ops (NOT vmcnt)
__device__ __forceinline__ void barrier_lgkm() {
    asm volatile("s_waitcnt lgkmcnt(0)\ns_barrier" ::: "memory");
}
__device__ __forceinline__ half8 load_wrow8(const float* p) {
    const float4* q = (const float4*)p;
    float4 a = q[0], b = q[1];
    half8 r;
    r[0] = (_Float16)a.x; r[1] = (_Float16)a.y; r[2] = (_Float16)a.z; r[3] = (_Float16)a.w;
    r[4] = (_Float16)b.x; r[5] = (_Float16)b.y; r[6] = (_Float16)b.z; r[7] = (_Float16)b.w;
    return r;
}
// scaled variant: w -> f16(w * s). Folds log2(e) into gate weights so the
// scan's sigmoid/tanh use raw v_exp_f32 (exp2) with no pre-multiply.
__device__ __forceinline__ half8 load_wrow8s(const float* p, float s) {
    const float4* q = (const float4*)p;
    float4 a = q[0], b = q[1];
    half8 r;
    r[0] = (_Float16)(a.x * s); r[1] = (_Float16)(a.y * s);
    r[2] = (_Float16)(a.z * s); r[3] = (_Float16)(a.w * s);
    r[4] = (_Float16)(b.x * s); r[5] = (_Float16)(b.y * s);
    r[6] = (_Float16)(b.z * s); r[7] = (_Float16)(b.w * s);
    return r;
}
// split f32x8 into hi(f16) + lo(f16 of residual): hi+lo reproduces f32 to ~2^-22
__device__ __forceinline__ void split8(const float* v, half8& hi, half8& lo) {
    #pragma unroll
    for (int j = 0; j < 8; ++j) {
        _Float16 h = (_Float16)v[j];
        hi[j] = h;
        lo[j] = (_Float16)(v[j] - (float)h);
    }
}
#define MM16(A_, B_, C_) __builtin_amdgcn_mfma_f32_16x16x32_f16(A_, B_, C_, 0, 0, 0)

// ---------------------------------------------------------------------------
// K1: dilated conv + BN + exact GELU via MFMA (split-f16 for f32 accuracy).
// x tile staged into LDS once (coalesced), pre-split into f16 hi/lo planes.
// z stored via LDS transpose tile -> coalesced global stores.
// ---------------------------------------------------------------------------
__global__ __launch_bounds__(256) void conv_mfma_kernel(
    const float* __restrict__ x, const float* __restrict__ mix_w,
    const float* __restrict__ bn_g, const float* __restrict__ bn_b,
    const float* __restrict__ bn_m, const float* __restrict__ bn_v,
    u32* __restrict__ z_out)
{
    __shared__ __align__(16) u32 xs[132 * 68];
    __shared__ __align__(8)  u32 zt[16 * 34];

    const int b   = blockIdx.y;
    const int t0  = blockIdx.x * 128;
    const int tid = threadIdx.x;
    const int wv = tid >> 6;
    const int lane = tid & 63;
    const int lane15 = lane & 15;
    const int quad = lane >> 4;

    {
        const float* xb = x + (size_t)b * TT * FF;
        for (int idx = tid; idx < 132 * 32; idx += 256) {
            const int row = idx >> 5;
            const int fp  = (idx & 31) * 2;
            const int t = t0 - 2 + row;
            float v0 = 0.f, v1 = 0.f;
            if (t >= 0 && t < TT) {
                float2 v = *(const float2*)(xb + (size_t)t * FF + fp);
                v0 = v.x; v1 = v.y;
            }
            _Float16 h0 = (_Float16)v0, h1 = (_Float16)v1;
            _Float16 l0 = (_Float16)(v0 - (float)h0);
            _Float16 l1 = (_Float16)(v1 - (float)h1);
            u32* rw = xs + row * 68;
            rw[(fp >> 1)]      = packhh(h0, h1);
            rw[32 + (fp >> 1)] = packhh(l0, l1);
        }
    }

    half8 Ahi[6], Alo[6];
    {
        const int fo = wv * 16 + lane15;
        const float* wrow = mix_w + fo * 192;
        #pragma unroll
        for (int s = 0; s < 6; ++s) {
            float wf[8];
            #pragma unroll
            for (int j = 0; j < 8; ++j) {
                int kap = s * 32 + quad * 8 + j;
                wf[j] = wrow[(kap & 63) * 3 + (kap >> 6)];
            }
            split8(wf, Ahi[s], Alo[s]);
        }
    }
    float sc[4], sh[4];
    #pragma unroll
    for (int r = 0; r < 4; ++r) {
        int f = wv * 16 + quad * 4 + r;
        float scl = bn_g[f] * rsqrtf(bn_v[f] + 1e-5f);
        sc[r] = scl; sh[r] = bn_b[f] - bn_m[f] * scl;
    }

    __syncthreads();

    u32* zrow = z_out + (size_t)(b >> 4) * TT * 512 + (b & 15) * 32;
    const int srow = tid >> 4;
    const int sc2  = tid & 15;

    for (int tt = 0; tt < 8; ++tt) {
        f32x4 C = {0.f, 0.f, 0.f, 0.f};
        #pragma unroll
        for (int s = 0; s < 6; ++s) {
            const int row = tt * 16 + lane15 + 2 * (s >> 1);
            const u32* rp = xs + row * 68 + (s & 1) * 16 + quad * 4;
            half8 Bhi = __builtin_bit_cast(half8, *(const uint4*)(rp));
            half8 Blo = __builtin_bit_cast(half8, *(const uint4*)(rp + 32));
            C = MM16(Ahi[s], Bhi, C);
            C = MM16(Ahi[s], Blo, C);
            C = MM16(Alo[s], Bhi, C);
        }
        float z0 = gelu_exact(fmaf(C[0], sc[0], sh[0]));
        float z1 = gelu_exact(fmaf(C[1], sc[1], sh[1]));
        float z2 = gelu_exact(fmaf(C[2], sc[2], sh[2]));
        float z3 = gelu_exact(fmaf(C[3], sc[3], sh[3]));
        const u32 q0 = packh2(z0, z1);
        const u32 q1 = packh2(z2, z3);
        __syncthreads();
        *(uint2*)(zt + lane15 * 34 + wv * 8 + quad * 2) = (uint2){q0, q1};
        __syncthreads();
        uint2 v = *(const uint2*)(zt + srow * 34 + sc2 * 2);
        *(uint2*)(zrow + (size_t)(t0 + tt * 16 + srow) * 512 + sc2 * 2) = v;
    }
}

// ---------------------------------------------------------------------------
// GEMM device body (MFMA): xg[t][tile][chain][n'/2] f16 pairs. 512 workers.
// Weights/biases pre-scaled by L2E (r,z: tiles 0..19) / TL2E (n: 20..29).
// ---------------------------------------------------------------------------
#define DECLAI(i) half8 A##i##_0, A##i##_1, A##i##_2, A##i##_3, A##i##_4;
#define GLOADA(i) { int tl = wv4 + (i); int rowc = tl < 30 ? tl * 16 + lane15 : 479; \
    float sA = tl < 20 ? L2E : TL2E;                                                 \
    const float* wp = W + (size_t)rowc * K + quad * 8;                               \
    A##i##_0 = load_wrow8s(wp, sA); A##i##_1 = load_wrow8s(wp + 32, sA);             \
    if (KT > 2) { A##i##_2 = load_wrow8s(wp + 64, sA);                               \
                  A##i##_3 = load_wrow8s(wp + 96, sA);                               \
                  A##i##_4 = load_wrow8s(wp + 128, sA); }                            \
    else { A##i##_2 = A##i##_0; A##i##_3 = A##i##_0; A##i##_4 = A##i##_0; } }
#define GMM(i, kt) C##i = MM16(A##i##_##kt, Bk##kt, C##i);

template<int K, int KT, int TG>
__device__ __forceinline__ void gemm_body(
    const unsigned short* __restrict__ in,
    size_t in_blk_stride, int t_off,
    const float* __restrict__ W, const float* __restrict__ b_ih,
    const float* __restrict__ b_hh, u32* __restrict__ xg,
    int gidx, int tid)
{
    if (tid >= 512) return;
    const int wv4 = (tid >> 6) * 4;
    const int lane = tid & 63;
    const int lane15 = lane & 15;
    const int quad = lane >> 4;
    const int blk = gidx >> 4;
    const int tbase = (gidx & 15) * TG;

    DECLAI(0) DECLAI(1) DECLAI(2) DECLAI(3)
    GLOADA(0) GLOADA(1) GLOADA(2) GLOADA(3)

    f32x4 BIAS0, BIAS1, BIAS2, BIAS3;
    #define GBIAS(i) { int tl = wv4 + (i); int rowb = tl < 30 ? tl * 16 + quad * 4 : 476; \
        float sB = tl < 20 ? L2E : TL2E;                                                  \
        float4 bi = *(const float4*)(b_ih + rowb);                                        \
        if (tl < 20) { float4 bh = *(const float4*)(b_hh + rowb);                         \
            bi.x += bh.x; bi.y += bh.y; bi.z += bh.z; bi.w += bh.w; }                     \
        BIAS##i[0] = bi.x * sB; BIAS##i[1] = bi.y * sB;                                   \
        BIAS##i[2] = bi.z * sB; BIAS##i[3] = bi.w * sB; }
    GBIAS(0) GBIAS(1) GBIAS(2) GBIAS(3)
    #undef GBIAS

    const unsigned short* inb = in + (size_t)blk * in_blk_stride;
    u32* xgb = xg + (size_t)blk * TC * 3840;

    for (int t = 0; t < TG; ++t) {
        const int tt = tbase + t;
        const unsigned short* ip =
            inb + ((size_t)(t_off + tt) * 16 + lane15) * K + quad * 8;
        half8 Bk0 = __builtin_bit_cast(half8, *(const uint4*)(ip));
        half8 Bk1 = __builtin_bit_cast(half8, *(const uint4*)(ip + 32));
        half8 Bk2 = Bk0, Bk3 = Bk0, Bk4 = Bk0;
        if (KT > 2) {
            Bk2 = __builtin_bit_cast(half8, *(const uint4*)(ip + 64));
            Bk3 = __builtin_bit_cast(half8, *(const uint4*)(ip + 96));
            Bk4 = __builtin_bit_cast(half8, *(const uint4*)(ip + 128));
        }
        f32x4 C0 = BIAS0, C1 = BIAS1, C2 = BIAS2, C3 = BIAS3;
        GMM(0, 0) GMM(1, 0) GMM(2, 0) GMM(3, 0)
        GMM(0, 1) GMM(1, 1) GMM(2, 1) GMM(3, 1)
        if (KT > 2) {
            GMM(0, 2) GMM(1, 2) GMM(2, 2) GMM(3, 2)
            GMM(0, 3) GMM(1, 3) GMM(2, 3) GMM(3, 3)
            GMM(0, 4) GMM(1, 4) GMM(2, 4) GMM(3, 4)
        }
        #define GSTORE(i) { int tl = wv4 + (i); if (tl < 30) {                      \
            u32 q0 = packh2(C##i[0], C##i[1]);                                      \
            u32 q1 = packh2(C##i[2], C##i[3]);                                      \
            *(uint2*)(xgb + (((size_t)tt * 30 + tl) * 16 + lane15) * 8 + quad * 2)  \
                = (uint2){q0, q1}; } }
        GSTORE(0) GSTORE(1) GSTORE(2) GSTORE(3)
        #undef GSTORE
    }
}

// ---------------------------------------------------------------------------
// Scan device body: 640 threads, 10 waves, *** 8 chains per block ***.
// The 8 chains are duplicated across the 16 MFMA B-columns (lane15 and
// lane15+8 read identical LDS addresses -> broadcast). sel = lane15>>3
// splits the 4 C-rows between the duplicate lanes, so each lane computes
// only 2 gate triples: 12 trans + ~22 gate VALU (halved vs 16-chain).
// C-init {lo,hi,lo,hi} makes the used half correct without lane selects.
// LDS layout per parity: [band 20][chain 8][4 u32] (2560 B).
// ---------------------------------------------------------------------------
#define DECLW(nm) half8 nm##0, nm##1, nm##2, nm##3, nm##4;
#define LOADWHS(nm, tb, S) { const float* wp = w_hh + (size_t)((tb) * 16 + lane15) * HH + quad * 8; \
    nm##0 = load_wrow8s(wp, S);       nm##1 = load_wrow8s(wp + 32, S);                              \
    nm##2 = load_wrow8s(wp + 64, S);  nm##3 = load_wrow8s(wp + 96, S);                              \
    nm##4 = load_wrow8s(wp + 128, S); }

template<bool WRITE_H>
__device__ __forceinline__ void scan_body(
    const u32* __restrict__ xg,          // f16 pairs [4][TC][30][16][8] u32
    const float* __restrict__ w_hh, const float* __restrict__ b_hh,
    float* __restrict__ h_state,         // [64][160] f32 carry
    u32* __restrict__ h_out32,           // [4][TC][16][80] u32 (if WRITE_H)
    int first, int blk, int half, int tid, uint4* h_lds)
{
    const int wv = tid >> 6;
    const int lane = tid & 63;
    const int lane15 = lane & 15;
    const int quad = lane >> 4;
    const int ch   = lane15 & 7;      // chain within the block's 8
    const int sel  = lane15 >> 3;     // row-pair select (0: rows 0,1; 1: rows 2,3)
    const int ch0  = half * 8;        // global chain base within blk

    DECLW(Ar) DECLW(Az) DECLW(An)
    LOADWHS(Ar, wv, L2E) LOADWHS(Az, 10 + wv, L2E) LOADWHS(An, 20 + wv, TL2E)

    // n-gate bias for this lane's 2 rows
    const float2 bhn2 = *(const float2*)(b_hh + 320 + wv * 16 + quad * 4 + 2 * sel);
    const float bh0 = bhn2.x * TL2E, bh1 = bhn2.y * TL2E;

    // h carry: 2 f32 (rows 16wv + 4q + 2sel + {0,1}, chain ch0+ch)
    float* hsp = h_state + (size_t)(blk * 16 + ch0 + ch) * HH
               + wv * 16 + quad * 4 + 2 * sel;
    float2 ho = {0.f, 0.f};
    if (!first) ho = *(const float2*)hsp;

    // LDS write index: band = 2wv + (q>>1); slot = 2(q&1)+sel
    const int hwidx = (((2 * wv + (quad >> 1)) * 8 + ch) << 2) + 2 * (quad & 1) + sel;
    u32* hl32 = (u32*)h_lds;
    u32* HW0 = hl32 + hwidx;             // parity 0
    u32* HW1 = hl32 + 640 + hwidx;       // parity 1
    *HW0 = packh2(ho.x, ho.y);

    // B-fragment read base (uint4 units): vb + 32*i, lanes lane15/lane15+8 alias
    const int vb = 8 * quad + ch;

    const u32* xgb = xg + (size_t)blk * TC * 3840;
    const int xo_r = (((wv)      * 16 + ch0 + ch) << 3) + quad * 2 + sel;
    const int xo_z = (((10 + wv) * 16 + ch0 + ch) << 3) + quad * 2 + sel;
    const int xo_n = (((20 + wv) * 16 + ch0 + ch) << 3) + quad * 2 + sel;

    // 4-deep prefetch ring: 3 u32 per step
    u32 xrP0 = xgb[0 * 3840 + xo_r], xzP0 = xgb[0 * 3840 + xo_z], xnP0 = xgb[0 * 3840 + xo_n];
    u32 xrP1 = xgb[1 * 3840 + xo_r], xzP1 = xgb[1 * 3840 + xo_z], xnP1 = xgb[1 * 3840 + xo_n];
    u32 xrP2 = xgb[2 * 3840 + xo_r], xzP2 = xgb[2 * 3840 + xo_z], xnP2 = xgb[2 * 3840 + xo_n];
    u32 xrP3 = xgb[3 * 3840 + xo_r], xzP3 = xgb[3 * 3840 + xo_z], xnP3 = xgb[3 * 3840 + xo_n];
    const u32* pf_r = xgb + 4 * 3840 + xo_r;
    const u32* pf_z = xgb + 4 * 3840 + xo_z;
    const u32* pf_n = xgb + 4 * 3840 + xo_n;

    u32* hp = WRITE_H
            ? h_out32 + (size_t)blk * TC * 1280 + (size_t)(ch0 + ch) * 80
              + wv * 8 + quad * 2 + sel
            : nullptr;
    __syncthreads();

    #define SCAN_STEP(RBOFF, HWP, XR, XZ, XN, PFO, HPO)                              \
    {                                                                                \
        const uint4* hb = h_lds + (RBOFF);                                           \
        uint4 b0 = hb[vb];       uint4 b1 = hb[vb + 32];                             \
        uint4 b2 = hb[vb + 64];  uint4 b3 = hb[vb + 96];                             \
        uint4 b4 = hb[vb + 128];                                                     \
        f32x4 Cr, Cz, Cn;                                                            \
        float xr0 = h2lo(XR), xr1 = h2hi(XR);                                        \
        Cr[0] = xr0; Cr[1] = xr1; Cr[2] = xr0; Cr[3] = xr1;                          \
        float xz0 = h2lo(XZ), xz1 = h2hi(XZ);                                        \
        Cz[0] = xz0; Cz[1] = xz1; Cz[2] = xz0; Cz[3] = xz1;                          \
        Cn[0] = bh0; Cn[1] = bh1; Cn[2] = bh0; Cn[3] = bh1;                          \
        float xn0 = h2lo(XN), xn1 = h2hi(XN);                                        \
        XR = pf_r[PFO]; XZ = pf_z[PFO]; XN = pf_n[PFO];                              \
        half8 B0 = __builtin_bit_cast(half8, b0);                                    \
        Cr = MM16(Ar0, B0, Cr); Cz = MM16(Az0, B0, Cz); Cn = MM16(An0, B0, Cn);      \
        half8 B1 = __builtin_bit_cast(half8, b1);                                    \
        Cr = MM16(Ar1, B1, Cr); Cz = MM16(Az1, B1, Cz); Cn = MM16(An1, B1, Cn);      \
        half8 B2 = __builtin_bit_cast(half8, b2);                                    \
        Cr = MM16(Ar2, B2, Cr); Cz = MM16(Az2, B2, Cz); Cn = MM16(An2, B2, Cn);      \
        half8 B3 = __builtin_bit_cast(half8, b3);                                    \
        Cr = MM16(Ar3, B3, Cr); Cz = MM16(Az3, B3, Cz); Cn = MM16(An3, B3, Cn);      \
        half8 B4 = __builtin_bit_cast(half8, b4);                                    \
        Cr = MM16(Ar4, B4, Cr); Cz = MM16(Az4, B4, Cz); Cn = MM16(An4, B4, Cn);      \
        {                                                                            \
            float cr0 = sel ? Cr[2] : Cr[0], cr1 = sel ? Cr[3] : Cr[1];              \
            float cz0 = sel ? Cz[2] : Cz[0], cz1 = sel ? Cz[3] : Cz[1];              \
            float cn0 = sel ? Cn[2] : Cn[0], cn1 = sel ? Cn[3] : Cn[1];              \
            float r0 = frcp(1.f + fexp2(-cr0));                                      \
            float r1 = frcp(1.f + fexp2(-cr1));                                      \
            float u0 = frcp(1.f + fexp2(-cz0));                                      \
            float u1 = frcp(1.f + fexp2(-cz1));                                      \
            float e0 = fexp2(fmaf(r0, cn0, xn0));                                    \
            float e1 = fexp2(fmaf(r1, cn1, xn1));                                    \
            float n0 = fmaf(-2.f, frcp(e0 + 1.f), 1.f);                              \
            float n1 = fmaf(-2.f, frcp(e1 + 1.f), 1.f);                              \
            ho.x = fmaf(u0, ho.x - n0, n0);                                          \
            ho.y = fmaf(u1, ho.y - n1, n1);                                          \
        }                                                                            \
        const u32 p = packh2(ho.x, ho.y);                                            \
        *(HWP) = p;                                                                  \
        if (WRITE_H) { hp[HPO] = p; }                                                \
        barrier_lgkm();                                                              \
    }

    for (int t4 = 0; t4 < TC; t4 += 4) {
        SCAN_STEP(0,   HW1, xrP0, xzP0, xnP0, 0 * 3840, 0 * 1280)
        SCAN_STEP(160, HW0, xrP1, xzP1, xnP1, 1 * 3840, 1 * 1280)
        SCAN_STEP(0,   HW1, xrP2, xzP2, xnP2, 2 * 3840, 2 * 1280)
        SCAN_STEP(160, HW0, xrP3, xzP3, xnP3, 3 * 3840, 3 * 1280)
        pf_r += 4 * 3840; pf_z += 4 * 3840; pf_n += 4 * 3840;
        if (WRITE_H) hp += 4 * 1280;
    }
    #undef SCAN_STEP

    *(float2*)hsp = ho;
}

// ---------------------------------------------------------------------------
// K2: pipelined mega-dispatch. Stage k runs concurrently:
//   blocks 0..7    : scan1 chunk k-1   (8 blocks: blk = bx>>1, half = bx&1)
//   blocks 8..15   : scan2 chunk k-3
//   blocks 16..79  : gemm1 chunk k     (64 blocks, TG=8)
//   blocks 80..143 : gemm2 chunk k-2   (64 blocks, TG=8)
// Producer->consumer edges cross dispatch boundaries; parity (chunk&1)
// double-buffers xg1/xg2/h1c against same-dispatch writers.
// Scan prefetch over-reads <=4 steps past its region; stays inside ws.
// ---------------------------------------------------------------------------
__global__ __launch_bounds__(640, 1) void pipe_stage(
    const u32* __restrict__ z,           // [4][TT][16][32] u32
    u32* __restrict__ xg1,               // 2 x [4][TC][3840] u32
    u32* __restrict__ xg2,
    u32* __restrict__ h1c,               // 2 x [4][TC][1280] u32
    float* __restrict__ h1s, float* __restrict__ h2s,
    const float* __restrict__ w_ih1, const float* __restrict__ b_ih1,
    const float* __restrict__ w_hh1, const float* __restrict__ b_hh1,
    const float* __restrict__ w_ih2, const float* __restrict__ b_ih2,
    const float* __restrict__ w_hh2, const float* __restrict__ b_hh2,
    int k)
{
    __shared__ uint4 h_lds[2 * 160];
    const int bx = blockIdx.x;
    const int tid = threadIdx.x;
    const size_t XGCH = (size_t)4 * TC * 3840;   // u32 per parity buffer
    const size_t H1CH = (size_t)4 * TC * 1280;

    if (bx < 8) {
        const int c = k - 1;
        if (c < 0 || c >= NC) return;
        scan_body<true>(xg1 + (c & 1) * XGCH, w_hh1, b_hh1, h1s,
                        h1c + (c & 1) * H1CH, c == 0, bx >> 1, bx & 1, tid, h_lds);
    } else if (bx < 16) {
        const int c = k - 3;
        if (c < 0 || c >= NC) return;
        scan_body<false>(xg2 + (c & 1) * XGCH, w_hh2, b_hh2, h2s,
                         nullptr, c == 0, (bx - 8) >> 1, (bx - 8) & 1, tid, h_lds);
    } else if (bx < 80) {
        const int c = k;
        if (c >= NC) return;
        gemm_body<64, 2, 8>((const unsigned short*)z, (size_t)TT * 1024, c * TC,
                            w_ih1, b_ih1, b_hh1, xg1 + (c & 1) * XGCH, bx - 16, tid);
    } else {
        const int c = k - 2;
        if (c < 0 || c >= NC) return;
        gemm_body<160, 5, 8>((const unsigned short*)(h1c + (c & 1) * H1CH),
                             (size_t)TC * 2560, 0,
                             w_ih2, b_ih2, b_hh2, xg2 + (c & 1) * XGCH, bx - 80, tid);
    }
}

// ---------------------------------------------------------------------------
// K3: MLP head from h2 final state.
// ---------------------------------------------------------------------------
__global__ __launch_bounds__(256) void head_kernel(
    const float* __restrict__ h_state,
    const float* __restrict__ hw1, const float* __restrict__ hb1,
    const float* __restrict__ hw2, const float* __restrict__ hb2,
    float* __restrict__ out)
{
    const int b = blockIdx.x;
    const int tid = threadIdx.x;
    __shared__ float hf[HH];
    __shared__ float q[80];
    if (tid < HH) hf[tid] = h_state[b * HH + tid];
    __syncthreads();
    if (tid < 80) {
        float a = hb1[tid];
        const float* wr = hw1 + (size_t)tid * HH;
        #pragma unroll 8
        for (int i = 0; i < HH; ++i) a = fmaf(wr[i], hf[i], a);
        q[tid] = gelu_exact(a);
    }
    __syncthreads();
    if (tid < 2) {
        float o = hb2[tid];
        const float* wr = hw2 + tid * 80;
        #pragma unroll 8
        for (int j = 0; j < 80; ++j) o = fmaf(wr[j], q[j], o);
        out[b * 2 + tid] = o;
    }
}

// ---------------------------------------------------------------------------
extern "C" void kernel_launch(void* const* d_in, const int* in_sizes, int n_in,
                              void* d_out, int out_size, void* d_ws, size_t ws_size,
                              hipStream_t stream)
{
    const float* x     = (const float*)d_in[0];
    const float* mix_w = (const float*)d_in[1];
    const float* bn_g  = (const float*)d_in[2];
    const float* bn_b  = (const float*)d_in[3];
    const float* bn_m  = (const float*)d_in[4];
    const float* bn_v  = (const float*)d_in[5];
    const float* w_ih1 = (const float*)d_in[6];
    const float* w_hh1 = (const float*)d_in[7];
    const float* b_ih1 = (const float*)d_in[8];
    const float* b_hh1 = (const float*)d_in[9];
    const float* w_ih2 = (const float*)d_in[10];
    const float* w_hh2 = (const float*)d_in[11];
    const float* b_ih2 = (const float*)d_in[12];
    const float* b_hh2 = (const float*)d_in[13];
    const float* hw1   = (const float*)d_in[14];
    const float* hb1   = (const float*)d_in[15];
    const float* hw2   = (const float*)d_in[16];
    const float* hb2   = (const float*)d_in[17];
    float* out = (float*)d_out;

    // ws (53.6 MB, proven-safe):
    //   z    f16 [4][T][16][64]            16.78 MB
    //   xg1  f16 2x[4][TC][30][16][16]     15.73 MB
    //   xg2  f16 2x[4][TC][30][16][16]     15.73 MB
    //   h1c  f16 2x[4][TC][16][160]         5.24 MB
    //   h1s,h2s f32 [64][160]               2 x 40 KB
    char* p = (char*)d_ws;
    u32* z_ws  = (u32*)p;  p += (size_t)BB * TT * 32 * 4;
    u32* xg1_ws = (u32*)p; p += (size_t)2 * 4 * TC * 3840 * 4;
    u32* xg2_ws = (u32*)p; p += (size_t)2 * 4 * TC * 3840 * 4;
    u32* h1c_ws = (u32*)p; p += (size_t)2 * 4 * TC * 1280 * 4;
    float* h1s = (float*)p; p += (size_t)BB * HH * 4;
    float* h2s = (float*)p;

    conv_mfma_kernel<<<dim3(16, BB), 256, 0, stream>>>(
        x, mix_w, bn_g, bn_b, bn_m, bn_v, z_ws);

    for (int k = 0; k <= NC + 2; ++k) {
        pipe_stage<<<144, 640, 0, stream>>>(
            z_ws, xg1_ws, xg2_ws, h1c_ws, h1s, h2s,
            w_ih1, b_ih1, w_hh1, b_hh1,
            w_ih2, b_ih2, w_hh2, b_hh2, k);
    }

    head_kernel<<<BB, 256, 0, stream>>>(h2s, hw1, hb1, hw2, hb2, out);
}

// Round 8
// 1614.591 us; speedup vs baseline: 1.3034x; 1.1612x over previous
//
#include <hip/hip_runtime.h>
#include <cmath>

#define BB 64
#define TT 2048
#define FF 64
#define HH 160
#define G3 480
#define TC 128            // time-chunk length
#define NC (TT / TC)      // 16 chunks

#define L2E  1.44269504088896340736f
#define TL2E 2.88539008177792681472f

typedef unsigned int u32;
typedef _Float16 half8 __attribute__((ext_vector_type(8)));
typedef _Float16 half2v __attribute__((ext_vector_type(2)));
typedef float f32x4 __attribute__((ext_vector_type(4)));

__device__ __forceinline__ unsigned short f2h(float v) {
    _Float16 h = (_Float16)v;
    return __builtin_bit_cast(unsigned short, h);
}
__device__ __forceinline__ u32 packh2(float a, float b) {
    return (u32)f2h(a) | ((u32)f2h(b) << 16);
}
__device__ __forceinline__ u32 packhh(_Float16 a, _Float16 b) {
    return (u32)__builtin_bit_cast(unsigned short, a)
         | ((u32)__builtin_bit_cast(unsigned short, b) << 16);
}
__device__ __forceinline__ float h2lo(u32 p) {
    return (float)__builtin_bit_cast(half2v, p)[0];
}
__device__ __forceinline__ float h2hi(u32 p) {
    return (float)__builtin_bit_cast(half2v, p)[1];
}
// select f16 half by precomputed shift (0 or 16), then convert
__device__ __forceinline__ float h2sel(u32 p, u32 sh) {
    return (float)__builtin_bit_cast(half2v, p >> sh)[0];
}
// fast 1-ulp reciprocal / exp2 (avoid IEEE div + libm: no fast-math in harness)
__device__ __forceinline__ float frcp(float v) { return __builtin_amdgcn_rcpf(v); }
#if __has_builtin(__builtin_amdgcn_exp2f)
__device__ __forceinline__ float fexp2(float v) { return __builtin_amdgcn_exp2f(v); }
#else
__device__ __forceinline__ float fexp2(float v) { return __expf(v * 0.69314718055994530942f); }
#endif
__device__ __forceinline__ float gelu_exact(float v) {
    return 0.5f * v * (1.f + erff(v * 0.70710678118654752f));
}
// barrier that waits only on LDS ops (NOT vmcnt)
__device__ __forceinline__ void barrier_lgkm() {
    asm volatile("s_waitcnt lgkmcnt(0)\ns_barrier" ::: "memory");
}
// scaled variant: w -> f16(w * s). Folds log2(e) into gate weights so the
// scan's sigmoid/tanh use raw v_exp_f32 (exp2) with no pre-multiply.
__device__ __forceinline__ half8 load_wrow8s(const float* p, float s) {
    const float4* q = (const float4*)p;
    float4 a = q[0], b = q[1];
    half8 r;
    r[0] = (_Float16)(a.x * s); r[1] = (_Float16)(a.y * s);
    r[2] = (_Float16)(a.z * s); r[3] = (_Float16)(a.w * s);
    r[4] = (_Float16)(b.x * s); r[5] = (_Float16)(b.y * s);
    r[6] = (_Float16)(b.z * s); r[7] = (_Float16)(b.w * s);
    return r;
}
// split f32x8 into hi(f16) + lo(f16 of residual): hi+lo reproduces f32 to ~2^-22
__device__ __forceinline__ void split8(const float* v, half8& hi, half8& lo) {
    #pragma unroll
    for (int j = 0; j < 8; ++j) {
        _Float16 h = (_Float16)v[j];
        hi[j] = h;
        lo[j] = (_Float16)(v[j] - (float)h);
    }
}
#define MM16(A_, B_, C_) __builtin_amdgcn_mfma_f32_16x16x32_f16(A_, B_, C_, 0, 0, 0)

// ---------------------------------------------------------------------------
// K1: dilated conv + BN + exact GELU via MFMA (split-f16 for f32 accuracy).
// R8: 64-t tiles (19 KB LDS -> 8 blocks/CU, 2048 blocks). x staged into LDS
// once (coalesced, pre-split hi/lo); z stored via LDS transpose tile.
// ---------------------------------------------------------------------------
__global__ __launch_bounds__(256) void conv_mfma_kernel(
    const float* __restrict__ x, const float* __restrict__ mix_w,
    const float* __restrict__ bn_g, const float* __restrict__ bn_b,
    const float* __restrict__ bn_m, const float* __restrict__ bn_v,
    u32* __restrict__ z_out)
{
    __shared__ __align__(16) u32 xs[68 * 68];
    __shared__ __align__(8)  u32 zt[16 * 34];

    const int b   = blockIdx.y;
    const int t0  = blockIdx.x * 64;
    const int tid = threadIdx.x;
    const int wv = tid >> 6;
    const int lane = tid & 63;
    const int lane15 = lane & 15;
    const int quad = lane >> 4;

    {
        const float* xb = x + (size_t)b * TT * FF;
        for (int idx = tid; idx < 68 * 32; idx += 256) {
            const int row = idx >> 5;
            const int fp  = (idx & 31) * 2;
            const int t = t0 - 2 + row;
            float v0 = 0.f, v1 = 0.f;
            if (t >= 0 && t < TT) {
                float2 v = *(const float2*)(xb + (size_t)t * FF + fp);
                v0 = v.x; v1 = v.y;
            }
            _Float16 h0 = (_Float16)v0, h1 = (_Float16)v1;
            _Float16 l0 = (_Float16)(v0 - (float)h0);
            _Float16 l1 = (_Float16)(v1 - (float)h1);
            u32* rw = xs + row * 68;
            rw[(fp >> 1)]      = packhh(h0, h1);
            rw[32 + (fp >> 1)] = packhh(l0, l1);
        }
    }

    half8 Ahi[6], Alo[6];
    {
        const int fo = wv * 16 + lane15;
        const float* wrow = mix_w + fo * 192;
        #pragma unroll
        for (int s = 0; s < 6; ++s) {
            float wf[8];
            #pragma unroll
            for (int j = 0; j < 8; ++j) {
                int kap = s * 32 + quad * 8 + j;
                wf[j] = wrow[(kap & 63) * 3 + (kap >> 6)];
            }
            split8(wf, Ahi[s], Alo[s]);
        }
    }
    float sc[4], sh[4];
    #pragma unroll
    for (int r = 0; r < 4; ++r) {
        int f = wv * 16 + quad * 4 + r;
        float scl = bn_g[f] * rsqrtf(bn_v[f] + 1e-5f);
        sc[r] = scl; sh[r] = bn_b[f] - bn_m[f] * scl;
    }

    __syncthreads();

    u32* zrow = z_out + (size_t)(b >> 4) * TT * 512 + (b & 15) * 32;
    const int srow = tid >> 4;
    const int sc2  = tid & 15;

    for (int tt = 0; tt < 4; ++tt) {
        f32x4 C = {0.f, 0.f, 0.f, 0.f};
        #pragma unroll
        for (int s = 0; s < 6; ++s) {
            const int row = tt * 16 + lane15 + 2 * (s >> 1);
            const u32* rp = xs + row * 68 + (s & 1) * 16 + quad * 4;
            half8 Bhi = __builtin_bit_cast(half8, *(const uint4*)(rp));
            half8 Blo = __builtin_bit_cast(half8, *(const uint4*)(rp + 32));
            C = MM16(Ahi[s], Bhi, C);
            C = MM16(Ahi[s], Blo, C);
            C = MM16(Alo[s], Bhi, C);
        }
        float z0 = gelu_exact(fmaf(C[0], sc[0], sh[0]));
        float z1 = gelu_exact(fmaf(C[1], sc[1], sh[1]));
        float z2 = gelu_exact(fmaf(C[2], sc[2], sh[2]));
        float z3 = gelu_exact(fmaf(C[3], sc[3], sh[3]));
        const u32 q0 = packh2(z0, z1);
        const u32 q1 = packh2(z2, z3);
        __syncthreads();
        *(uint2*)(zt + lane15 * 34 + wv * 8 + quad * 2) = (uint2){q0, q1};
        __syncthreads();
        uint2 v = *(const uint2*)(zt + srow * 34 + sc2 * 2);
        *(uint2*)(zrow + (size_t)(t0 + tt * 16 + srow) * 512 + sc2 * 2) = v;
    }
}

// ---------------------------------------------------------------------------
// GEMM device body (MFMA): xg[t][tile][chain][n'/2] f16 pairs. 512 workers.
// Weights/biases pre-scaled by L2E (r,z: tiles 0..19) / TL2E (n: 20..29).
// ---------------------------------------------------------------------------
#define DECLAI(i) half8 A##i##_0, A##i##_1, A##i##_2, A##i##_3, A##i##_4;
#define GLOADA(i) { int tl = wv4 + (i); int rowc = tl < 30 ? tl * 16 + lane15 : 479; \
    float sA = tl < 20 ? L2E : TL2E;                                                 \
    const float* wp = W + (size_t)rowc * K + quad * 8;                               \
    A##i##_0 = load_wrow8s(wp, sA); A##i##_1 = load_wrow8s(wp + 32, sA);             \
    if (KT > 2) { A##i##_2 = load_wrow8s(wp + 64, sA);                               \
                  A##i##_3 = load_wrow8s(wp + 96, sA);                               \
                  A##i##_4 = load_wrow8s(wp + 128, sA); }                            \
    else { A##i##_2 = A##i##_0; A##i##_3 = A##i##_0; A##i##_4 = A##i##_0; } }
#define GMM(i, kt) C##i = MM16(A##i##_##kt, Bk##kt, C##i);

template<int K, int KT, int TG>
__device__ __forceinline__ void gemm_body(
    const unsigned short* __restrict__ in,
    size_t in_blk_stride, int t_off,
    const float* __restrict__ W, const float* __restrict__ b_ih,
    const float* __restrict__ b_hh, u32* __restrict__ xg,
    int gidx, int tid)
{
    if (tid >= 512) return;
    const int wv4 = (tid >> 6) * 4;
    const int lane = tid & 63;
    const int lane15 = lane & 15;
    const int quad = lane >> 4;
    const int blk = gidx >> 4;
    const int tbase = (gidx & 15) * TG;

    DECLAI(0) DECLAI(1) DECLAI(2) DECLAI(3)
    GLOADA(0) GLOADA(1) GLOADA(2) GLOADA(3)

    f32x4 BIAS0, BIAS1, BIAS2, BIAS3;
    #define GBIAS(i) { int tl = wv4 + (i); int rowb = tl < 30 ? tl * 16 + quad * 4 : 476; \
        float sB = tl < 20 ? L2E : TL2E;                                                  \
        float4 bi = *(const float4*)(b_ih + rowb);                                        \
        if (tl < 20) { float4 bh = *(const float4*)(b_hh + rowb);                         \
            bi.x += bh.x; bi.y += bh.y; bi.z += bh.z; bi.w += bh.w; }                     \
        BIAS##i[0] = bi.x * sB; BIAS##i[1] = bi.y * sB;                                   \
        BIAS##i[2] = bi.z * sB; BIAS##i[3] = bi.w * sB; }
    GBIAS(0) GBIAS(1) GBIAS(2) GBIAS(3)
    #undef GBIAS

    const unsigned short* inb = in + (size_t)blk * in_blk_stride;
    u32* xgb = xg + (size_t)blk * TC * 3840;

    for (int t = 0; t < TG; ++t) {
        const int tt = tbase + t;
        const unsigned short* ip =
            inb + ((size_t)(t_off + tt) * 16 + lane15) * K + quad * 8;
        half8 Bk0 = __builtin_bit_cast(half8, *(const uint4*)(ip));
        half8 Bk1 = __builtin_bit_cast(half8, *(const uint4*)(ip + 32));
        half8 Bk2 = Bk0, Bk3 = Bk0, Bk4 = Bk0;
        if (KT > 2) {
            Bk2 = __builtin_bit_cast(half8, *(const uint4*)(ip + 64));
            Bk3 = __builtin_bit_cast(half8, *(const uint4*)(ip + 96));
            Bk4 = __builtin_bit_cast(half8, *(const uint4*)(ip + 128));
        }
        f32x4 C0 = BIAS0, C1 = BIAS1, C2 = BIAS2, C3 = BIAS3;
        GMM(0, 0) GMM(1, 0) GMM(2, 0) GMM(3, 0)
        GMM(0, 1) GMM(1, 1) GMM(2, 1) GMM(3, 1)
        if (KT > 2) {
            GMM(0, 2) GMM(1, 2) GMM(2, 2) GMM(3, 2)
            GMM(0, 3) GMM(1, 3) GMM(2, 3) GMM(3, 3)
            GMM(0, 4) GMM(1, 4) GMM(2, 4) GMM(3, 4)
        }
        #define GSTORE(i) { int tl = wv4 + (i); if (tl < 30) {                      \
            u32 q0 = packh2(C##i[0], C##i[1]);                                      \
            u32 q1 = packh2(C##i[2], C##i[3]);                                      \
            *(uint2*)(xgb + (((size_t)tt * 30 + tl) * 16 + lane15) * 8 + quad * 2)  \
                = (uint2){q0, q1}; } }
        GSTORE(0) GSTORE(1) GSTORE(2) GSTORE(3)
        #undef GSTORE
    }
}

// ---------------------------------------------------------------------------
// Scan device body: 640 threads, 10 waves, *** 4 chains per block ***.
// Chains duplicated 4x across the 16 MFMA B-columns (col -> chain = col&3);
// dup = lane15>>2 picks 1 of the 4 C-rows, so each lane computes exactly ONE
// gate triple: 6 trans + ~25 VALU. h carry is 1 f32/lane; LDS h write is one
// ds_write_b16. LDS layout per parity: [chain:4][160 f16 + 8 pad] (336 B
// stride -> chains land on distinct bank phases {0,20,8,28}).
// ---------------------------------------------------------------------------
#define DECLW(nm) half8 nm##0, nm##1, nm##2, nm##3, nm##4;
#define LOADWHS(nm, tb, S) { const float* wp = w_hh + (size_t)((tb) * 16 + lane15) * HH + quad * 8; \
    nm##0 = load_wrow8s(wp, S);       nm##1 = load_wrow8s(wp + 32, S);                              \
    nm##2 = load_wrow8s(wp + 64, S);  nm##3 = load_wrow8s(wp + 96, S);                              \
    nm##4 = load_wrow8s(wp + 128, S); }

template<bool WRITE_H>
__device__ __forceinline__ void scan_body(
    const u32* __restrict__ xg,          // f16 pairs [4][TC][30][16][8] u32
    const float* __restrict__ w_hh, const float* __restrict__ b_hh,
    float* __restrict__ h_state,         // [64][160] f32 carry
    u32* __restrict__ h_out32,           // [4][TC][16][160] f16 (if WRITE_H)
    int first, int blk, int sub, int tid, u32* h_lds32)
{
    const int wv = tid >> 6;
    const int lane = tid & 63;
    const int lane15 = lane & 15;
    const int quad = lane >> 4;
    const int ch   = lane15 & 3;      // chain within the block's 4
    const int dup  = lane15 >> 2;     // row select within C (0..3)
    const int ch0  = sub * 4;         // global chain base within blk
    const int row_g = wv * 16 + quad * 4 + dup;   // h row this lane owns
    const u32 shamt = (u32)(16 * (dup & 1));
    const bool d1 = (dup & 1) != 0;
    const bool d2 = (dup & 2) != 0;

    DECLW(Ar) DECLW(Az) DECLW(An)
    LOADWHS(Ar, wv, L2E) LOADWHS(Az, 10 + wv, L2E) LOADWHS(An, 20 + wv, TL2E)

    const float bh = b_hh[320 + row_g] * TL2E;   // n-gate hidden bias, this row

    float* hsp = h_state + (size_t)(blk * 16 + ch0 + ch) * HH + row_g;
    float ho = first ? 0.f : *hsp;

    // LDS u16 index: chain base 168 u16 (336 B) + row
    const int widx = ch * 168 + row_g;
    unsigned short* hw16 = (unsigned short*)h_lds32;
    unsigned short* HW0 = hw16 + widx;           // parity 0
    unsigned short* HW1 = hw16 + 672 + widx;     // parity 1 (336 u32)
    *HW0 = f2h(ho);

    // fragment read base (uint4 units): chain*21 + quad; slice stride 4
    const int vb = ch * 21 + quad;

    const u32* xgb = xg + (size_t)blk * TC * 3840;
    const int pr = quad * 2 + (dup >> 1);        // u32 pair slot within tile row
    const int xo_r = ((wv)      * 16 + ch0 + ch) * 8 + pr;
    const int xo_z = ((10 + wv) * 16 + ch0 + ch) * 8 + pr;
    const int xo_n = ((20 + wv) * 16 + ch0 + ch) * 8 + pr;

    // 4-deep prefetch ring: 3 u32 per step
    u32 xrP0 = xgb[0 * 3840 + xo_r], xzP0 = xgb[0 * 3840 + xo_z], xnP0 = xgb[0 * 3840 + xo_n];
    u32 xrP1 = xgb[1 * 3840 + xo_r], xzP1 = xgb[1 * 3840 + xo_z], xnP1 = xgb[1 * 3840 + xo_n];
    u32 xrP2 = xgb[2 * 3840 + xo_r], xzP2 = xgb[2 * 3840 + xo_z], xnP2 = xgb[2 * 3840 + xo_n];
    u32 xrP3 = xgb[3 * 3840 + xo_r], xzP3 = xgb[3 * 3840 + xo_z], xnP3 = xgb[3 * 3840 + xo_n];
    const u32* pf_r = xgb + 4 * 3840 + xo_r;
    const u32* pf_z = xgb + 4 * 3840 + xo_z;
    const u32* pf_n = xgb + 4 * 3840 + xo_n;

    // h1c: f16 at [blk][t][chain 16][row 160]
    unsigned short* hp = WRITE_H
            ? (unsigned short*)h_out32 + (size_t)blk * TC * 2560
              + (size_t)(ch0 + ch) * 160 + row_g
            : nullptr;
    __syncthreads();

    #define SCAN_STEP(RBOFF, HWP, XR, XZ, XN, PFO, HPO)                              \
    {                                                                                \
        const uint4* hb = (const uint4*)(h_lds32 + (RBOFF));                         \
        uint4 b0 = hb[vb];      uint4 b1 = hb[vb + 4];                               \
        uint4 b2 = hb[vb + 8];  uint4 b3 = hb[vb + 12];                              \
        uint4 b4 = hb[vb + 16];                                                      \
        float xrv = h2sel(XR, shamt);                                                \
        float xzv = h2sel(XZ, shamt);                                                \
        float xnv = h2sel(XN, shamt);                                                \
        f32x4 Cr = {xrv, xrv, xrv, xrv};                                             \
        f32x4 Cz = {xzv, xzv, xzv, xzv};                                             \
        f32x4 Cn = {bh, bh, bh, bh};                                                 \
        XR = pf_r[PFO]; XZ = pf_z[PFO]; XN = pf_n[PFO];                              \
        half8 B0 = __builtin_bit_cast(half8, b0);                                    \
        Cr = MM16(Ar0, B0, Cr); Cz = MM16(Az0, B0, Cz); Cn = MM16(An0, B0, Cn);      \
        half8 B1 = __builtin_bit_cast(half8, b1);                                    \
        Cr = MM16(Ar1, B1, Cr); Cz = MM16(Az1, B1, Cz); Cn = MM16(An1, B1, Cn);      \
        half8 B2 = __builtin_bit_cast(half8, b2);                                    \
        Cr = MM16(Ar2, B2, Cr); Cz = MM16(Az2, B2, Cz); Cn = MM16(An2, B2, Cn);      \
        half8 B3 = __builtin_bit_cast(half8, b3);                                    \
        Cr = MM16(Ar3, B3, Cr); Cz = MM16(Az3, B3, Cz); Cn = MM16(An3, B3, Cn);      \
        half8 B4 = __builtin_bit_cast(half8, b4);                                    \
        Cr = MM16(Ar4, B4, Cr); Cz = MM16(Az4, B4, Cz); Cn = MM16(An4, B4, Cn);      \
        {                                                                            \
            float ca = d1 ? Cr[1] : Cr[0];                                           \
            float cb = d1 ? Cr[3] : Cr[2];                                           \
            float crv = d2 ? cb : ca;                                                \
            ca = d1 ? Cz[1] : Cz[0];                                                 \
            cb = d1 ? Cz[3] : Cz[2];                                                 \
            float czv = d2 ? cb : ca;                                                \
            ca = d1 ? Cn[1] : Cn[0];                                                 \
            cb = d1 ? Cn[3] : Cn[2];                                                 \
            float cnv = d2 ? cb : ca;                                                \
            float r = frcp(1.f + fexp2(-crv));                                       \
            float u = frcp(1.f + fexp2(-czv));                                       \
            float e = fexp2(fmaf(r, cnv, xnv));                                      \
            float n = fmaf(-2.f, frcp(e + 1.f), 1.f);                                \
            ho = fmaf(u, ho - n, n);                                                 \
        }                                                                            \
        const unsigned short hv = f2h(ho);                                           \
        *(HWP) = hv;                                                                 \
        if (WRITE_H) { hp[HPO] = hv; }                                               \
        barrier_lgkm();                                                              \
    }

    for (int t4 = 0; t4 < TC; t4 += 4) {
        SCAN_STEP(0,   HW1, xrP0, xzP0, xnP0, 0 * 3840, 0 * 2560)
        SCAN_STEP(336, HW0, xrP1, xzP1, xnP1, 1 * 3840, 1 * 2560)
        SCAN_STEP(0,   HW1, xrP2, xzP2, xnP2, 2 * 3840, 2 * 2560)
        SCAN_STEP(336, HW0, xrP3, xzP3, xnP3, 3 * 3840, 3 * 2560)
        pf_r += 4 * 3840; pf_z += 4 * 3840; pf_n += 4 * 3840;
        if (WRITE_H) hp += 4 * 2560;
    }
    #undef SCAN_STEP

    *hsp = ho;
}

// ---------------------------------------------------------------------------
// K2: pipelined mega-dispatch. Stage k runs concurrently:
//   blocks 0..15   : scan1 chunk k-1   (blk = bx>>2, sub = bx&3)
//   blocks 16..31  : scan2 chunk k-3
//   blocks 32..95  : gemm1 chunk k     (64 blocks, TG=8)
//   blocks 96..159 : gemm2 chunk k-2   (64 blocks, TG=8)
// Producer->consumer edges cross dispatch boundaries; parity (chunk&1)
// double-buffers xg1/xg2/h1c against same-dispatch writers.
// Scan prefetch over-reads <=4 steps past its region; stays inside ws.
// ---------------------------------------------------------------------------
__global__ __launch_bounds__(640, 1) void pipe_stage(
    const u32* __restrict__ z,           // [4][TT][16][32] u32
    u32* __restrict__ xg1,               // 2 x [4][TC][3840] u32
    u32* __restrict__ xg2,
    u32* __restrict__ h1c,               // 2 x [4][TC][1280] u32
    float* __restrict__ h1s, float* __restrict__ h2s,
    const float* __restrict__ w_ih1, const float* __restrict__ b_ih1,
    const float* __restrict__ w_hh1, const float* __restrict__ b_hh1,
    const float* __restrict__ w_ih2, const float* __restrict__ b_ih2,
    const float* __restrict__ w_hh2, const float* __restrict__ b_hh2,
    int k)
{
    __shared__ __align__(16) u32 h_lds32[2 * 336];
    const int bx = blockIdx.x;
    const int tid = threadIdx.x;
    const size_t XGCH = (size_t)4 * TC * 3840;   // u32 per parity buffer
    const size_t H1CH = (size_t)4 * TC * 1280;

    if (bx < 16) {
        const int c = k - 1;
        if (c < 0 || c >= NC) return;
        scan_body<true>(xg1 + (c & 1) * XGCH, w_hh1, b_hh1, h1s,
                        h1c + (c & 1) * H1CH, c == 0, bx >> 2, bx & 3, tid, h_lds32);
    } else if (bx < 32) {
        const int c = k - 3;
        if (c < 0 || c >= NC) return;
        scan_body<false>(xg2 + (c & 1) * XGCH, w_hh2, b_hh2, h2s,
                         nullptr, c == 0, (bx - 16) >> 2, (bx - 16) & 3, tid, h_lds32);
    } else if (bx < 96) {
        const int c = k;
        if (c >= NC) return;
        gemm_body<64, 2, 8>((const unsigned short*)z, (size_t)TT * 1024, c * TC,
                            w_ih1, b_ih1, b_hh1, xg1 + (c & 1) * XGCH, bx - 32, tid);
    } else {
        const int c = k - 2;
        if (c < 0 || c >= NC) return;
        gemm_body<160, 5, 8>((const unsigned short*)(h1c + (c & 1) * H1CH),
                             (size_t)TC * 2560, 0,
                             w_ih2, b_ih2, b_hh2, xg2 + (c & 1) * XGCH, bx - 96, tid);
    }
}

// ---------------------------------------------------------------------------
// K3: MLP head from h2 final state.
// ---------------------------------------------------------------------------
__global__ __launch_bounds__(256) void head_kernel(
    const float* __restrict__ h_state,
    const float* __restrict__ hw1, const float* __restrict__ hb1,
    const float* __restrict__ hw2, const float* __restrict__ hb2,
    float* __restrict__ out)
{
    const int b = blockIdx.x;
    const int tid = threadIdx.x;
    __shared__ float hf[HH];
    __shared__ float q[80];
    if (tid < HH) hf[tid] = h_state[b * HH + tid];
    __syncthreads();
    if (tid < 80) {
        float a = hb1[tid];
        const float* wr = hw1 + (size_t)tid * HH;
        #pragma unroll 8
        for (int i = 0; i < HH; ++i) a = fmaf(wr[i], hf[i], a);
        q[tid] = gelu_exact(a);
    }
    __syncthreads();
    if (tid < 2) {
        float o = hb2[tid];
        const float* wr = hw2 + tid * 80;
        #pragma unroll 8
        for (int j = 0; j < 80; ++j) o = fmaf(wr[j], q[j], o);
        out[b * 2 + tid] = o;
    }
}

// ---------------------------------------------------------------------------
extern "C" void kernel_launch(void* const* d_in, const int* in_sizes, int n_in,
                              void* d_out, int out_size, void* d_ws, size_t ws_size,
                              hipStream_t stream)
{
    const float* x     = (const float*)d_in[0];
    const float* mix_w = (const float*)d_in[1];
    const float* bn_g  = (const float*)d_in[2];
    const float* bn_b  = (const float*)d_in[3];
    const float* bn_m  = (const float*)d_in[4];
    const float* bn_v  = (const float*)d_in[5];
    const float* w_ih1 = (const float*)d_in[6];
    const float* w_hh1 = (const float*)d_in[7];
    const float* b_ih1 = (const float*)d_in[8];
    const float* b_hh1 = (const float*)d_in[9];
    const float* w_ih2 = (const float*)d_in[10];
    const float* w_hh2 = (const float*)d_in[11];
    const float* b_ih2 = (const float*)d_in[12];
    const float* b_hh2 = (const float*)d_in[13];
    const float* hw1   = (const float*)d_in[14];
    const float* hb1   = (const float*)d_in[15];
    const float* hw2   = (const float*)d_in[16];
    const float* hb2   = (const float*)d_in[17];
    float* out = (float*)d_out;

    // ws (53.6 MB, proven-safe):
    //   z    f16 [4][T][16][64]            16.78 MB
    //   xg1  f16 2x[4][TC][30][16][16]     15.73 MB
    //   xg2  f16 2x[4][TC][30][16][16]     15.73 MB
    //   h1c  f16 2x[4][TC][16][160]         5.24 MB
    //   h1s,h2s f32 [64][160]               2 x 40 KB
    char* p = (char*)d_ws;
    u32* z_ws  = (u32*)p;  p += (size_t)BB * TT * 32 * 4;
    u32* xg1_ws = (u32*)p; p += (size_t)2 * 4 * TC * 3840 * 4;
    u32* xg2_ws = (u32*)p; p += (size_t)2 * 4 * TC * 3840 * 4;
    u32* h1c_ws = (u32*)p; p += (size_t)2 * 4 * TC * 1280 * 4;
    float* h1s = (float*)p; p += (size_t)BB * HH * 4;
    float* h2s = (float*)p;

    conv_mfma_kernel<<<dim3(32, BB), 256, 0, stream>>>(
        x, mix_w, bn_g, bn_b, bn_m, bn_v, z_ws);

    for (int k = 0; k <= NC + 2; ++k) {
        pipe_stage<<<160, 640, 0, stream>>>(
            z_ws, xg1_ws, xg2_ws, h1c_ws, h1s, h2s,
            w_ih1, b_ih1, w_hh1, b_hh1,
            w_ih2, b_ih2, w_hh2, b_hh2, k);
    }

    head_kernel<<<BB, 256, 0, stream>>>(h2s, hw1, hb1, hw2, hb2, out);
}